// Round 5
// baseline (2021.442 us; speedup 1.0000x reference)
//
#include <hip/hip_runtime.h>

// VQ argmin: exact bit-level emulation of numpy fp32 reference:
//   A  = np.sum(flat*flat, axis=1)     (numpy pairwise-sum tree, fp32)
//   M2 = (2*flat) @ emb.T              (BLAS: sequential fp32 fma chain over d)
//   dist = (A - M2) + ee;  argmin_k (first-min ties)
// out: int32 [65536]
//
// R5: z staged ONCE into LDS (64n x 256d = 64 KB/block); e fed via VECTOR
// uniform-broadcast loads (opaque v_mov_b32-0 taint defeats the compiler's
// scalarization -> vmcnt-pipelined global_load_dwordx4, escaping the SMEM
// out-of-order lgkmcnt(0)-drain wall that capped R3/R4 at ~65% VALU).
// In-block k-split x4, LDS combine. z HBM traffic 2 GB -> 64 MB.

#define D_DIM  256
#define K_DIM  1024
#define HW     4096
#define N_TOT  65536
#define KT     16                 // k per acc group
#define NLB    64                 // n per block
#define KSP    4                  // k-splits per block (ks = tid>>6, wave-uniform)
#define KRANGE (K_DIM / KSP)      // 256 k per thread
#define NPASS  (KRANGE / KT)      // 16
#define F32MAX 3.402823466e38f

// ---- numpy pairwise_sum replication (n=256 = two 128-blocks of 8 accumulators)

__global__ void ee_kernel(const float* __restrict__ e, float* __restrict__ ee) {
#pragma clang fp contract(off)
    int k = blockIdx.x * blockDim.x + threadIdx.x;
    if (k >= K_DIM) return;
    const float* row = e + (size_t)k * D_DIM;
    float total = 0.0f;
    #pragma unroll
    for (int h = 0; h < 2; ++h) {
        const float* a = row + h * 128;
        float r[8];
        #pragma unroll
        for (int j = 0; j < 8; ++j) { float v = a[j]; r[j] = v * v; }
        #pragma unroll
        for (int i = 8; i < 128; i += 8) {
            #pragma unroll
            for (int j = 0; j < 8; ++j) { float v = a[i + j]; r[j] = r[j] + v * v; }
        }
        float s = ((r[0] + r[1]) + (r[2] + r[3])) + ((r[4] + r[5]) + (r[6] + r[7]));
        total = (h == 0) ? s : (total + s);
    }
    ee[k] = total;
}

__global__ void a_kernel(const float* __restrict__ z, float* __restrict__ A) {
#pragma clang fp contract(off)
    int n = blockIdx.x * blockDim.x + threadIdx.x;
    int b  = n >> 12;
    int hw = n & (HW - 1);
    const float* base = z + (size_t)b * D_DIM * HW + hw;
    float total = 0.0f;
    #pragma unroll
    for (int h = 0; h < 2; ++h) {
        float r[8];
        #pragma unroll
        for (int j = 0; j < 8; ++j) {
            float v = base[(size_t)(h * 128 + j) * HW];
            r[j] = v * v;
        }
        #pragma unroll
        for (int i = 8; i < 128; i += 8) {
            #pragma unroll
            for (int j = 0; j < 8; ++j) {
                float v = base[(size_t)(h * 128 + i + j) * HW];
                r[j] = r[j] + v * v;
            }
        }
        float s = ((r[0] + r[1]) + (r[2] + r[3])) + ((r[4] + r[5]) + (r[6] + r[7]));
        total = (h == 0) ? s : (total + s);
    }
    A[n] = total;
}

// ---- pack: epk[((k>>4)*256 + d)*16 + (k&15)] = 2*emb[k][d]
// per (ks,pass): 256 dd x 64 B sequential stream; x2 exact (exponent shift)

__global__ void pack_kernel(const float* __restrict__ e, float* __restrict__ epk) {
    int k = blockIdx.x;       // 0..1023
    int d = threadIdx.x;      // 0..255
    epk[((size_t)(k >> 4) * D_DIM + d) * KT + (k & 15)] = 2.0f * e[(size_t)k * D_DIM + d];
}

// ---- main: z in LDS once; e via broadcast vector loads; in-block k-split

__launch_bounds__(256, 2)
__global__ void vq_main(const float* __restrict__ z, const float* __restrict__ epk,
                        const float* __restrict__ A, const float* __restrict__ ee,
                        int* __restrict__ out) {
#pragma clang fp contract(off)
    __shared__ __align__(16) unsigned char smem[D_DIM * NLB * 4];   // 64 KB
    float* zs = (float*)smem;                                        // [d][n]

    const int tid = threadIdx.x;
    const int nl  = tid & (NLB - 1);
    const int ks  = tid >> 6;               // wave-pair uniform k-split
    const int n0  = blockIdx.x * NLB;       // NLB | HW: never crosses batch
    const int b   = n0 >> 12;
    const int hw0 = n0 & (HW - 1);
    const float* __restrict__ zbase = z + (size_t)b * D_DIM * HW + hw0;

    // stage z once: 16 float4/thread, coalesced; LDS writes 2-way max (free)
    #pragma unroll
    for (int rep = 0; rep < 16; ++rep) {
        int fidx = rep * 256 + tid;         // 0..4095
        int d  = fidx >> 4;
        int n4 = (fidx & 15) * 4;
        float4 v = *(const float4*)(zbase + (size_t)d * HW + n4);
        *(float4*)&zs[d * NLB + n4] = v;
    }
    __syncthreads();

    // opaque per-lane zero: compiler can't prove e-addresses uniform ->
    // keeps them as VECTOR loads (vmcnt-pipelined broadcast), not s_load.
    int lz;
    asm volatile("v_mov_b32 %0, 0" : "=v"(lz));
    const float* __restrict__ eb = epk + (size_t)ks * (NPASS * D_DIM * KT) + lz;

    const float An = A[n0 + nl];
    float bestv = F32MAX;
    int   bestk = 0;

    #pragma unroll 1
    for (int p = 0; p < NPASS; ++p) {
        const float* __restrict__ ep = eb + (size_t)p * (D_DIM * KT);
        float acc[KT];
        #pragma unroll
        for (int j = 0; j < KT; ++j) acc[j] = 0.0f;

        // software pipeline, depth 4 dd: e in float4 bufs, z via ds_read
        float4 ebuf[4][4];
        float  zbuf[4];
        #pragma unroll
        for (int s = 0; s < 4; ++s) {
            const float4* e4 = (const float4*)(ep + s * KT);
            ebuf[s][0] = e4[0]; ebuf[s][1] = e4[1];
            ebuf[s][2] = e4[2]; ebuf[s][3] = e4[3];
            zbuf[s] = zs[s * NLB + nl];
        }

        #pragma unroll 1
        for (int dd = 0; dd < D_DIM; dd += 4) {
            const bool pf = (dd + 4 < D_DIM);
            #pragma unroll
            for (int s = 0; s < 4; ++s) {
                const float zv = zbuf[s];
                const float4 e0 = ebuf[s][0], e1 = ebuf[s][1];
                const float4 e2 = ebuf[s][2], e3 = ebuf[s][3];
                // d = dd+s consumed; chains per k strictly d-ascending
                acc[ 0] = fmaf(zv, e0.x, acc[ 0]);
                acc[ 1] = fmaf(zv, e0.y, acc[ 1]);
                acc[ 2] = fmaf(zv, e0.z, acc[ 2]);
                acc[ 3] = fmaf(zv, e0.w, acc[ 3]);
                acc[ 4] = fmaf(zv, e1.x, acc[ 4]);
                acc[ 5] = fmaf(zv, e1.y, acc[ 5]);
                acc[ 6] = fmaf(zv, e1.z, acc[ 6]);
                acc[ 7] = fmaf(zv, e1.w, acc[ 7]);
                acc[ 8] = fmaf(zv, e2.x, acc[ 8]);
                acc[ 9] = fmaf(zv, e2.y, acc[ 9]);
                acc[10] = fmaf(zv, e2.z, acc[10]);
                acc[11] = fmaf(zv, e2.w, acc[11]);
                acc[12] = fmaf(zv, e3.x, acc[12]);
                acc[13] = fmaf(zv, e3.y, acc[13]);
                acc[14] = fmaf(zv, e3.z, acc[14]);
                acc[15] = fmaf(zv, e3.w, acc[15]);
                if (pf) {   // prefetch d = dd+4+s
                    const float4* e4 = (const float4*)(ep + (dd + 4 + s) * KT);
                    ebuf[s][0] = e4[0]; ebuf[s][1] = e4[1];
                    ebuf[s][2] = e4[2]; ebuf[s][3] = e4[3];
                    zbuf[s] = zs[(dd + 4 + s) * NLB + nl];
                }
            }
        }

        // epilogue: dist = (An - M2) + ee, k ascending -> first-min ties
        const int kb = ks * KRANGE + p * KT;
        #pragma unroll
        for (int j = 0; j < KT; ++j) {
            const float dist = (An - acc[j]) + ee[kb + j];
            if (dist < bestv) { bestv = dist; bestk = kb + j; }
        }
    }

    // combine the 4 k-splits per n (ks ascending = k ascending; strict <)
    __syncthreads();                             // all waves done reading zs
    float* cv = (float*)smem;                    // [KSP][NLB]
    int*   ck = (int*)(smem + KSP * NLB * 4);
    cv[ks * NLB + nl] = bestv;
    ck[ks * NLB + nl] = bestk;
    __syncthreads();
    if (ks == 0) {
        float bv = cv[nl];
        int   bk = ck[nl];
        #pragma unroll
        for (int s2 = 1; s2 < KSP; ++s2) {
            float v = cv[s2 * NLB + nl];
            int   k = ck[s2 * NLB + nl];
            if (v < bv) { bv = v; bk = k; }
        }
        out[n0 + nl] = bk;
    }
}

extern "C" void kernel_launch(void* const* d_in, const int* in_sizes, int n_in,
                              void* d_out, int out_size, void* d_ws, size_t ws_size,
                              hipStream_t stream) {
    const float* z   = (const float*)d_in[0];   // [16,256,64,64]
    const float* emb = (const float*)d_in[1];   // [1024,256]
    int* out = (int*)d_out;                     // [65536] int32

    float* wsA   = (float*)d_ws;                // 65536
    float* wsEE  = wsA + N_TOT;                 // 1024
    float* wsEPK = wsEE + K_DIM;                // 262144

    pack_kernel<<<K_DIM, 256, 0, stream>>>(emb, wsEPK);
    ee_kernel<<<K_DIM / 256, 256, 0, stream>>>(emb, wsEE);
    a_kernel<<<N_TOT / 256, 256, 0, stream>>>(z, wsA);
    vq_main<<<N_TOT / NLB, 256, 0, stream>>>(z, wsEPK, wsA, wsEE, out);
}

// Round 6
// 1337.492 us; speedup vs baseline: 1.5114x; 1.5114x over previous
//
#include <hip/hip_runtime.h>

// VQ argmin: exact bit-level emulation of numpy fp32 reference:
//   A  = np.sum(flat*flat, axis=1)     (numpy pairwise-sum tree, fp32)
//   M2 = (2*flat) @ emb.T              (BLAS: sequential fp32 fma chain over d)
//   dist = (A - M2) + ee;  argmin_k (first-min ties)
// out: int32 [65536]
//
// R6: refined R3 (scalar-broadcast e, the measured-best structure).
//  - NSPLIT=8 (2048 blocks) removes the 4-block/CU grid cap
//  - __launch_bounds__(256,5): target <=102 regs/wave -> 5 waves/SIMD
//  - wave-staggered kt order (readfirstlane-uniform) de-convoys the
//    per-dd s_load lgkmcnt(0) drains across waves
//  - argmin via order-independent packed-u64 lexicographic atomicMin
//    (positive-float bit order == value order; low word k = first-min ties)
//  - aux collapsed: prep(pack+ee+A+init) / vq / finalize = 3 launches
// KT=64 keeps z re-stream multiplicity at K/KT=16 (R4 showed KT=32 hits HBM).

#define D_DIM  256
#define K_DIM  1024
#define HW     4096
#define N_TOT  65536
#define NSPLIT 8
#define KSPL   (K_DIM / NSPLIT)   // 128
#define KT     64
#define NKT    (KSPL / KT)        // 2
#define F32MAX 3.402823466e38f

// ---- fused prep: blocks [0,1024) pack epk; [1024,1028) ee; [1028,1284) A+init

__global__ void prep_kernel(const float* __restrict__ e, const float* __restrict__ z,
                            float* __restrict__ epk, float* __restrict__ ee,
                            float* __restrict__ A, unsigned long long* __restrict__ packed) {
#pragma clang fp contract(off)
    const int bid = blockIdx.x;
    const int tid = threadIdx.x;

    if (bid < 1024) {
        // pack: epk[(g*256 + d)*64 + j] = 2*emb[k][d], g=k>>6, j=k&63
        // x2 is exact (exponent shift); z*(2e) == (2z)*e bitwise.
        const int k = bid, d = tid;
        const int g = k >> 6, j = k & 63;
        epk[((size_t)g * D_DIM + d) * KT + j] = 2.0f * e[(size_t)k * D_DIM + d];
        return;
    }
    if (bid < 1028) {
        // ee[k]: numpy pairwise tree (two 128-blocks of 8 interleaved accs)
        const int k = (bid - 1024) * 256 + tid;
        const float* row = e + (size_t)k * D_DIM;
        float total = 0.0f;
        #pragma unroll
        for (int h = 0; h < 2; ++h) {
            const float* a = row + h * 128;
            float r[8];
            #pragma unroll
            for (int j = 0; j < 8; ++j) { float v = a[j]; r[j] = v * v; }
            #pragma unroll
            for (int i = 8; i < 128; i += 8) {
                #pragma unroll
                for (int j = 0; j < 8; ++j) { float v = a[i + j]; r[j] = r[j] + v * v; }
            }
            float s = ((r[0] + r[1]) + (r[2] + r[3])) + ((r[4] + r[5]) + (r[6] + r[7]));
            total = (h == 0) ? s : (total + s);
        }
        ee[k] = total;
        return;
    }
    {
        // A[n]: same tree over z; also init packed[n] (no poison dependence)
        const int n = (bid - 1028) * 256 + tid;
        const int b  = n >> 12;
        const int hw = n & (HW - 1);
        const float* base = z + (size_t)b * D_DIM * HW + hw;
        float total = 0.0f;
        #pragma unroll
        for (int h = 0; h < 2; ++h) {
            float r[8];
            #pragma unroll
            for (int j = 0; j < 8; ++j) {
                float v = base[(size_t)(h * 128 + j) * HW];
                r[j] = v * v;
            }
            #pragma unroll
            for (int i = 8; i < 128; i += 8) {
                #pragma unroll
                for (int j = 0; j < 8; ++j) {
                    float v = base[(size_t)(h * 128 + i + j) * HW];
                    r[j] = r[j] + v * v;
                }
            }
            float s = ((r[0] + r[1]) + (r[2] + r[3])) + ((r[4] + r[5]) + (r[6] + r[7]));
            total = (h == 0) ? s : (total + s);
        }
        A[n] = total;
        packed[n] = ~0ULL;
    }
}

// ---- main: 1 n/thread, e via SGPR broadcast, staggered kt, atomicMin epilogue

__launch_bounds__(256, 5)
__global__ void vq_partial(const float* __restrict__ z, const float* __restrict__ epk,
                           const float* __restrict__ A, const float* __restrict__ ee,
                           unsigned long long* __restrict__ packed) {
#pragma clang fp contract(off)
    const int tid  = threadIdx.x;
    const int s    = blockIdx.x & (NSPLIT - 1);
    const int slab = blockIdx.x >> 3;            // 0..255
    const int n    = slab * 256 + tid;
    const int b    = n >> 12;
    const float* __restrict__ zp = z + (size_t)b * D_DIM * HW + (n & (HW - 1));
    // wave id via readfirstlane: provably uniform -> e-addressing stays scalar
    const int w = __builtin_amdgcn_readfirstlane(tid) >> 6;

    const float An = A[n];
    unsigned long long best = ~0ULL;

    // z ping-pong: 8 d's per half; (mod 256) wrap re-primes the next kt pass
    float za[8], zb[8];
    #pragma unroll
    for (int i = 0; i < 8; ++i) za[i] = zp[(size_t)i * HW];

    #pragma unroll 1
    for (int t = 0; t < NKT; ++t) {
        const int kt = t ^ (w & 1);              // stagger waves' s_load convoys
        const int g  = 2 * s + kt;               // e-group, uniform
        const float* __restrict__ ep = epk + (size_t)g * (D_DIM * KT);

        float acc[KT];
        #pragma unroll
        for (int j = 0; j < KT; ++j) acc[j] = 0.0f;

        #pragma unroll 1
        for (int it = 0; it < 16; ++it) {
            const int base = it * 16;
            // prefetch d = base+8 .. base+15
            #pragma unroll
            for (int i = 0; i < 8; ++i)
                zb[i] = zp[(size_t)((base + 8 + i) & (D_DIM - 1)) * HW];
            // compute d = base .. base+7 (ascending: exact chain)
            #pragma unroll
            for (int dd = 0; dd < 8; ++dd) {
                const float zv = za[dd];
                const float* __restrict__ er = ep + (size_t)(base + dd) * KT;
                #pragma unroll
                for (int j = 0; j < KT; ++j)
                    acc[j] = fmaf(zv, er[j], acc[j]);   // er[j]: s_load -> SGPR
            }
            // prefetch d = base+16 .. base+23 (mod 256)
            #pragma unroll
            for (int i = 0; i < 8; ++i)
                za[i] = zp[(size_t)((base + 16 + i) & (D_DIM - 1)) * HW];
            // compute d = base+8 .. base+15
            #pragma unroll
            for (int dd = 0; dd < 8; ++dd) {
                const float zv = zb[dd];
                const float* __restrict__ er = ep + (size_t)(base + 8 + dd) * KT;
                #pragma unroll
                for (int j = 0; j < KT; ++j)
                    acc[j] = fmaf(zv, er[j], acc[j]);
            }
        }

        // epilogue: dist = (An - M2) + ee; lexicographic (distbits, k) min.
        // dist in [~240,~280] > 0 -> IEEE bit order == value order;
        // low-word k -> ties resolve to lowest k == numpy first-min.
        const int kb = s * KSPL + kt * KT;
        #pragma unroll
        for (int j = 0; j < KT; ++j) {
            const float dist = (An - acc[j]) + ee[kb + j];
            const unsigned long long p =
                ((unsigned long long)__float_as_uint(dist) << 32) | (unsigned)(kb + j);
            if (p < best) best = p;
        }
    }

    atomicMin(&packed[n], best);   // device-scope: cross-XCD safe
}

__global__ void fin_kernel(const unsigned long long* __restrict__ packed,
                           int* __restrict__ out) {
    const int n = blockIdx.x * 256 + threadIdx.x;
    out[n] = (int)(unsigned)(packed[n] & 0xffffffffULL);
}

extern "C" void kernel_launch(void* const* d_in, const int* in_sizes, int n_in,
                              void* d_out, int out_size, void* d_ws, size_t ws_size,
                              hipStream_t stream) {
    const float* z   = (const float*)d_in[0];   // [16,256,64,64]
    const float* emb = (const float*)d_in[1];   // [1024,256]
    int* out = (int*)d_out;                     // [65536] int32

    unsigned long long* wsP = (unsigned long long*)d_ws;       // 65536 u64 (8-aligned)
    float* wsA   = (float*)(wsP + N_TOT);                      // 65536
    float* wsEE  = wsA + N_TOT;                                // 1024
    float* wsEPK = wsEE + K_DIM;                               // 262144

    prep_kernel<<<1284, 256, 0, stream>>>(emb, z, wsEPK, wsEE, wsA, wsP);
    vq_partial<<<(N_TOT / 256) * NSPLIT, 256, 0, stream>>>(z, wsEPK, wsA, wsEE, wsP);
    fin_kernel<<<N_TOT / 256, 256, 0, stream>>>(wsP, out);
}